// Round 1
// baseline (437.473 us; speedup 1.0000x reference)
//
#include <hip/hip_runtime.h>
#include <stdint.h>

// Bilinear: out[b,i,j,k] = sum_{p,q} x1[b,i,p] W[k,p,q] x2[b,j,q] + bias[k]
// B=8, L=256, P=Q=512, K=64.
//
//  - pre-convert W/x1/x2 -> bf16 into ws head (36 MiB)
//  - Stage A: S[(b,j),(k,p)] = sum_q X2b[(b,j),q] * Wb[(k,p),q]   (S bf16)
//  - Stage B: out[b,i,(j,k)] = sum_p X1b[i,p] * S_b[(j,k),p] + bias[k]
//
// GEMM: 256x256 tile, BK=64, 8 waves (2M x 4N), reg-staged (NO global_load_lds
// — diverged under graph replay in a prior session), double-buffered LDS with
// XOR bank swizzle (T2), raw s_barrier + lgkmcnt-only drain so prefetch loads
// stay in flight across barriers (T3/T4), setprio around MFMA (T5),
// bijective XCD block swizzle, m-minor for W-panel L2 reuse (T1).

typedef __bf16 bf16x8 __attribute__((ext_vector_type(8)));
typedef float  f32x4  __attribute__((ext_vector_type(4)));

#define KDIM 512
#define BM 256
#define BN 256
#define BK 64
#define NT (KDIM / BK)   // 8 K-tiles

__global__ __launch_bounds__(256) void f32_to_bf16_kernel(
    const float* __restrict__ in, __bf16* __restrict__ out, long n8)
{
    for (long i = blockIdx.x * 256L + threadIdx.x; i < n8; i += gridDim.x * 256L) {
        f32x4 a = *(const f32x4*)(in + i * 8);
        f32x4 b = *(const f32x4*)(in + i * 8 + 4);
        bf16x8 o;
        o[0]=(__bf16)a[0]; o[1]=(__bf16)a[1]; o[2]=(__bf16)a[2]; o[3]=(__bf16)a[3];
        o[4]=(__bf16)b[0]; o[5]=(__bf16)b[1]; o[6]=(__bf16)b[2]; o[7]=(__bf16)b[3];
        *(bf16x8*)(out + i * 8) = o;
    }
}

// ---- GEMM macros (operate on kernel locals) ----
#define GLOAD(kt) do { _Pragma("unroll") \
    for (int it_ = 0; it_ < 4; ++it_) { \
        rA[it_] = *(const bf16x8*)(gA + (long)it_ * 64 * KDIM + (kt) * BK); \
        rB[it_] = *(const bf16x8*)(gB + (long)it_ * 64 * KDIM + (kt) * BK); \
    } } while (0)

#define SSTORE(bi) do { _Pragma("unroll") \
    for (int it_ = 0; it_ < 4; ++it_) { \
        *(bf16x8*)((char*)&lds[bi][0][0] + it_ * 8192 + sbyte) = rA[it_]; \
        *(bf16x8*)((char*)&lds[bi][1][0] + it_ * 8192 + sbyte) = rB[it_]; \
    } } while (0)

#define FRAG_READ(bi, kk) do { \
    const char* sAc_ = (const char*)&lds[bi][0][0]; \
    const char* sBc_ = (const char*)&lds[bi][1][0]; \
    const int ko_ = (((kk) * 64 + krow * 16) ^ rsw); \
    _Pragma("unroll") for (int i_ = 0; i_ < 8; ++i_) \
        af[i_] = *(const bf16x8*)(sAc_ + (wm * 128 + i_ * 16 + lcol) * 128 + ko_); \
    _Pragma("unroll") for (int j_ = 0; j_ < 4; ++j_) \
        bfr[j_] = *(const bf16x8*)(sBc_ + (wn * 64 + j_ * 16 + lcol) * 128 + ko_); \
    } while (0)

#define MFMA_ALL do { _Pragma("unroll") \
    for (int i_ = 0; i_ < 8; ++i_) { _Pragma("unroll") \
        for (int j_ = 0; j_ < 4; ++j_) \
            acc[i_][j_] = __builtin_amdgcn_mfma_f32_16x16x32_bf16(af[i_], bfr[j_], acc[i_][j_], 0, 0, 0); \
    } } while (0)

// Raw barrier: drain LDS ops only. Global prefetch loads (vmcnt) stay in
// flight across the barrier — this is the whole point (T4).
#define BARRIER() do { \
    asm volatile("s_waitcnt lgkmcnt(0)" ::: "memory"); \
    __builtin_amdgcn_sched_barrier(0); \
    __builtin_amdgcn_s_barrier(); \
    __builtin_amdgcn_sched_barrier(0); \
    } while (0)

template <typename OutT>
__global__ __launch_bounds__(512, 2) void gemm_nt_256(
    const __bf16* __restrict__ A,    // [M x 512] row-major
    const __bf16* __restrict__ B,    // [N x 512] row-major  (C = A * B^T)
    OutT* __restrict__ C,            // [M x ldc] row-major
    const float* __restrict__ bias,  // nullptr, or [64]: adds bias[col & 63]
    int ldc, int mtiles,             // m-tiles per z-slice (m-minor tile order)
    long sA, long sB, long sC)       // per-z strides (elements)
{
    __shared__ __bf16 lds[2][2][BM * BK];   // [dbuf][A/B][256*64] = 128 KiB

    const int tid  = threadIdx.x;
    const int lane = tid & 63;
    const int wave = tid >> 6;        // 0..7
    const int wm   = wave & 1;        // 2 M-waves  (128 rows each)
    const int wn   = wave >> 1;       // 4 N-waves  (64 cols each)
    const int lcol = lane & 15;
    const int krow = (lane >> 4) & 3;
    const int rsw  = (lcol & 7) << 4; // read-side XOR swizzle (row&7)<<4

    // Bijective XCD swizzle over the flattened grid (m204 formula).
    long flat = (long)blockIdx.z * gridDim.x + blockIdx.x;
    long nwg  = (long)gridDim.x * gridDim.z;
    long q = nwg >> 3, r = nwg & 7;
    long xcd = flat & 7, lo = flat >> 3;
    long sz = (xcd < r ? xcd * (q + 1) : r * (q + 1) + (xcd - r) * q) + lo;
    const int z   = (int)(sz / (long)gridDim.x);
    const int rem = (int)(sz % (long)gridDim.x);
    const int n0 = (rem / mtiles) * BN;   // m-minor: same n-tile (W panel)
    const int m0 = (rem % mtiles) * BM;   // stays on one XCD's L2

    A += (long)z * sA + (long)m0 * KDIM;
    B += (long)z * sB + (long)n0 * KDIM;
    C += (long)z * sC;

    // Staging: 512 thr x 4 it x 16 B covers one 256x64 bf16 tile (A and B).
    const int srow  = tid >> 3;                       // 0..63 (+64*it)
    const int sbyte = srow * 128 + ((((tid & 7) * 16)) ^ ((srow & 7) << 4));
    const __bf16* gA = A + (long)srow * KDIM + (tid & 7) * 8;
    const __bf16* gB = B + (long)srow * KDIM + (tid & 7) * 8;

    bf16x8 rA[4], rB[4];
    f32x4 acc[8][4] = {};

    // Prologue: tile0 -> LDS buf0; tile1 -> regs (in flight).
    GLOAD(0);
    SSTORE(0);        // compiler inserts the needed vmcnt waits on rA/rB
    GLOAD(1);
    BARRIER();

    for (int t = 0; t < NT - 1; ++t) {
        const int cur = t & 1, nxt = cur ^ 1;
        {   // kk = 0: read frags, write next tile into other buffer,
            // issue prefetch of tile t+2, then MFMA.
            bf16x8 af[8], bfr[4];
            FRAG_READ(cur, 0);
            SSTORE(nxt);
            if (t + 2 < NT) GLOAD(t + 2);
            __builtin_amdgcn_s_setprio(1);
            MFMA_ALL;
            __builtin_amdgcn_s_setprio(0);
        }
        {   // kk = 1
            bf16x8 af[8], bfr[4];
            FRAG_READ(cur, 1);
            __builtin_amdgcn_s_setprio(1);
            MFMA_ALL;
            __builtin_amdgcn_s_setprio(0);
        }
        BARRIER();
    }
    {   // last tile (NT-1 = 7 -> buf 1), no staging
        bf16x8 af[8], bfr[4];
        FRAG_READ(1, 0);
        MFMA_ALL;
        FRAG_READ(1, 1);
        MFMA_ALL;
    }

    // Epilogue. C/D layout (16x16): col = lane&15, row = (lane>>4)*4 + reg.
#pragma unroll
    for (int j = 0; j < 4; ++j) {
        const int col = n0 + wn * 64 + j * 16 + lcol;
        const float badd = bias ? bias[col & 63] : 0.f;
#pragma unroll
        for (int i = 0; i < 8; ++i) {
            const int rowb = m0 + wm * 128 + i * 16 + krow * 4;
#pragma unroll
            for (int rr = 0; rr < 4; ++rr)
                C[(long)(rowb + rr) * ldc + col] = (OutT)(acc[i][j][rr] + badd);
        }
    }
}

extern "C" void kernel_launch(void* const* d_in, const int* in_sizes, int n_in,
                              void* d_out, int out_size, void* d_ws, size_t ws_size,
                              hipStream_t stream)
{
    (void)in_sizes; (void)n_in; (void)out_size;
    const float* x1f = (const float*)d_in[0];  // [8,256,512]
    const float* x2f = (const float*)d_in[1];  // [8,256,512]
    const float* Wf  = (const float*)d_in[2];  // [64,512,512]
    const float* bs  = (const float*)d_in[3];  // [64]
    float* out = (float*)d_out;                // [8,256,256,64]

    const long N_W = 64L * 512 * 512;
    const long N_X = 8L * 256 * 512;
    __bf16* Wb  = (__bf16*)d_ws;
    __bf16* x1b = Wb + N_W;
    __bf16* x2b = x1b + N_X;
    __bf16* S   = x2b + N_X;
    const size_t head_bytes = (size_t)(N_W + 2 * N_X) * sizeof(__bf16); // 36 MiB

    f32_to_bf16_kernel<<<2048, 256, 0, stream>>>(Wf,  Wb,  N_W / 8);
    f32_to_bf16_kernel<<<512,  256, 0, stream>>>(x1f, x1b, N_X / 8);
    f32_to_bf16_kernel<<<512,  256, 0, stream>>>(x2f, x2b, N_X / 8);

    const long ROWS_TOTAL = 2048;              // S rows = (b,j)
    const long ROW_ELEMS  = 32768;             // (k,p) per S row

    long rows_chunk = (ws_size > head_bytes)
        ? (long)((ws_size - head_bytes) / (ROW_ELEMS * sizeof(__bf16))) : 0;
    rows_chunk &= ~255L;
    if (rows_chunk < 256) rows_chunk = 256;
    if (rows_chunk > ROWS_TOTAL) rows_chunk = ROWS_TOTAL;

    for (long r0 = 0; r0 < ROWS_TOTAL; r0 += rows_chunk) {
        long rows = ROWS_TOTAL - r0;
        if (rows > rows_chunk) rows = rows_chunk;
        long nbc = rows >> 8;                  // whole b's this chunk
        int  mt  = (int)(rows >> 8);           // 256-row m-tiles

        // Stage A: S = X2b @ Wb^T.  M = rows, N = 32768, K = 512.
        dim3 gA((unsigned)((32768 / BN) * mt), 1, 1);
        gemm_nt_256<__bf16><<<gA, 512, 0, stream>>>(
            x2b + r0 * KDIM, Wb, S, nullptr, 32768, mt, 0, 0, 0);

        // Stage B: z-batched over this chunk's b's -> fp32 out (+bias).
        dim3 gB2(16384 / BN, 1, (unsigned)nbc);
        gemm_nt_256<float><<<gB2, 512, 0, stream>>>(
            x1b + r0 * KDIM,                   // X1_b rows
            S,                                 // S_b as [16384 x 512]
            out + r0 * 16384,                  // out_b as [256 x 16384]
            bs, 16384, 1,
            256L * KDIM, 256L * ROW_ELEMS, 256L * 16384);
    }
}

// Round 2
// 324.461 us; speedup vs baseline: 1.3483x; 1.3483x over previous
//
#include <hip/hip_runtime.h>
#include <stdint.h>

// Bilinear: out[b,i,j,k] = sum_{p,q} x1[b,i,p] W[k,p,q] x2[b,j,q] + bias[k]
// B=8, L=256, P=Q=512, K=64.
//
//  - pre-convert W/x1/x2 -> bf16 into ws head (36 MiB)
//  - Stage A: S[(b,j),(k,p)] = sum_q X2b[(b,j),q] * Wb[(k,p),q]   (S bf16)
//  - Stage B: out[b,i,(j,k)] = sum_p X1b[i,p] * S_b[(j,k),p] + bias[k]
//
// GEMM: m201-style 8-phase 256x256/BK=64 schedule, reg-staged (NO
// global_load_lds — diverged under graph replay in a prior session).
// Per K-tile: 4 quadrant phases, each = {ds_read frags | vmcnt(4) +
// ds_write one 16KB half-tile | issue next half's 2 global loads |
// s_barrier | lgkmcnt(0) | setprio(1) 16xMFMA setprio(0) | s_barrier}.
// 3 half-tiles (6 loads) stay in flight across barriers at all times.
// T2 XOR swizzle on LDS (bank conflicts = 0, proven R1). T1 bijective
// XCD swizzle, m-minor (FETCH 164->72 MB, proven R1). Epilogue
// j-innermost so each 128B C line completes in 4 consecutive stores.

typedef __bf16 bf16x8 __attribute__((ext_vector_type(8)));
typedef float  f32x4  __attribute__((ext_vector_type(4)));

#define KDIM 512
#define BM 256
#define BN 256
#define BK 64

__global__ __launch_bounds__(256) void f32_to_bf16_kernel(
    const float* __restrict__ in, __bf16* __restrict__ out, long n8)
{
    for (long i = blockIdx.x * 256L + threadIdx.x; i < n8; i += gridDim.x * 256L) {
        f32x4 a = *(const f32x4*)(in + i * 8);
        f32x4 b = *(const f32x4*)(in + i * 8 + 4);
        bf16x8 o;
        o[0]=(__bf16)a[0]; o[1]=(__bf16)a[1]; o[2]=(__bf16)a[2]; o[3]=(__bf16)a[3];
        o[4]=(__bf16)b[0]; o[5]=(__bf16)b[1]; o[6]=(__bf16)b[2]; o[7]=(__bf16)b[3];
        *(bf16x8*)(out + i * 8) = o;
    }
}

// ---- schedule primitives ----
#define VMW(N) do { \
    asm volatile("s_waitcnt vmcnt(" #N ")" ::: "memory"); \
    __builtin_amdgcn_sched_barrier(0); } while (0)

#define LGKM0() do { \
    asm volatile("s_waitcnt lgkmcnt(0)" ::: "memory"); \
    __builtin_amdgcn_sched_barrier(0); } while (0)

#define BAR_MID() do { \
    __builtin_amdgcn_sched_barrier(0); \
    __builtin_amdgcn_s_barrier(); \
    LGKM0(); \
    __builtin_amdgcn_s_setprio(1); } while (0)

#define BAR_END() do { \
    __builtin_amdgcn_s_setprio(0); \
    __builtin_amdgcn_sched_barrier(0); \
    __builtin_amdgcn_s_barrier(); \
    __builtin_amdgcn_sched_barrier(0); } while (0)

// half-tile h: 0=A rows 0-127, 1=A rows 128-255, 2=B rows 0-127, 3=B rows 128-255
// STAGE_L: issue 2 global_load_dwordx4 into reg slot s (per-thread 32B slice).
#define STAGE_L(s, kt, h) do { \
    const __bf16* g_ = (((h) < 2) ? gA : gB) + ((long)((h) & 1) * 128) * KDIM + (kt) * BK; \
    rs[s][0] = *(const bf16x8*)(g_); \
    rs[s][1] = *(const bf16x8*)(g_ + 64L * KDIM); } while (0)

// STAGE_W: 2 ds_write_b128 of slot s into buffer bi (swizzled layout).
#define STAGE_W(s, bi, h) do { \
    char* p_ = (char*)&lds[bi][(h) >> 1][0] + ((h) & 1) * 16384 + sbyte; \
    *(bf16x8*)(p_)        = rs[s][0]; \
    *(bf16x8*)(p_ + 8192) = rs[s][1]; } while (0)

// Quadrant fragment reads (swizzled): A half qi (8 reads), B half qj (4 reads).
#define RD_A(bi, qi) do { \
    const char* sA_ = (const char*)&lds[bi][0][0]; \
    _Pragma("unroll") for (int i2_ = 0; i2_ < 4; ++i2_) { \
        const int row_ = wm * 128 + (qi) * 64 + i2_ * 16 + lcol; \
        const int sw_ = (row_ & 7) << 4; \
        af[i2_][0] = *(const bf16x8*)(sA_ + row_ * 128 + ((krow * 16) ^ sw_)); \
        af[i2_][1] = *(const bf16x8*)(sA_ + row_ * 128 + ((64 + krow * 16) ^ sw_)); \
    } } while (0)

#define RD_B(bi, qj) do { \
    const char* sB_ = (const char*)&lds[bi][1][0]; \
    _Pragma("unroll") for (int j2_ = 0; j2_ < 2; ++j2_) { \
        const int row_ = wn * 64 + (qj) * 32 + j2_ * 16 + lcol; \
        const int sw_ = (row_ & 7) << 4; \
        bfr[j2_][0] = *(const bf16x8*)(sB_ + row_ * 128 + ((krow * 16) ^ sw_)); \
        bfr[j2_][1] = *(const bf16x8*)(sB_ + row_ * 128 + ((64 + krow * 16) ^ sw_)); \
    } } while (0)

#define MFMA_Q(qi, qj) do { \
    _Pragma("unroll") for (int i2_ = 0; i2_ < 4; ++i2_) \
    _Pragma("unroll") for (int j2_ = 0; j2_ < 2; ++j2_) \
    _Pragma("unroll") for (int kk_ = 0; kk_ < 2; ++kk_) \
        acc[(qi) * 4 + i2_][(qj) * 2 + j2_] = __builtin_amdgcn_mfma_f32_16x16x32_bf16( \
            af[i2_][kk_], bfr[j2_][kk_], acc[(qi) * 4 + i2_][(qj) * 2 + j2_], 0, 0, 0); \
    } while (0)

// One uniform iteration: K-tiles {2T (buf0), 2T+1 (buf1)}, 8 phases.
// Writes: p0-3 -> tile 2T+1 halves 0-3 into buf1; p4-7 -> tile 2T+2 into buf0.
// Issues: for the write 3 phases ahead. Slots SA..SH = (c+1)%3 FIFO ring.
#define ITER_UNIFORM(TT, SA,SB,SC,SD,SE,SF,SG,SH) do { \
  { bf16x8 af[4][2], bfr[2][2]; \
    RD_A(0,0); RD_B(0,0); \
    VMW(4); STAGE_W(SA, 1, 0); STAGE_L(SA, 2*(TT)+1, 3); \
    BAR_MID(); MFMA_Q(0,0); BAR_END(); \
    RD_B(0,1); \
    VMW(4); STAGE_W(SB, 1, 1); STAGE_L(SB, 2*(TT)+2, 0); \
    BAR_MID(); MFMA_Q(0,1); BAR_END(); \
    RD_A(0,1); RD_B(0,0); \
    VMW(4); STAGE_W(SC, 1, 2); STAGE_L(SC, 2*(TT)+2, 1); \
    BAR_MID(); MFMA_Q(1,0); BAR_END(); \
    RD_B(0,1); \
    VMW(4); STAGE_W(SD, 1, 3); STAGE_L(SD, 2*(TT)+2, 2); \
    BAR_MID(); MFMA_Q(1,1); BAR_END(); } \
  { bf16x8 af[4][2], bfr[2][2]; \
    RD_A(1,0); RD_B(1,0); \
    VMW(4); STAGE_W(SE, 0, 0); STAGE_L(SE, 2*(TT)+2, 3); \
    BAR_MID(); MFMA_Q(0,0); BAR_END(); \
    RD_B(1,1); \
    VMW(4); STAGE_W(SF, 0, 1); STAGE_L(SF, 2*(TT)+3, 0); \
    BAR_MID(); MFMA_Q(0,1); BAR_END(); \
    RD_A(1,1); RD_B(1,0); \
    VMW(4); STAGE_W(SG, 0, 2); STAGE_L(SG, 2*(TT)+3, 1); \
    BAR_MID(); MFMA_Q(1,0); BAR_END(); \
    RD_B(1,1); \
    VMW(4); STAGE_W(SH, 0, 3); STAGE_L(SH, 2*(TT)+3, 2); \
    BAR_MID(); MFMA_Q(1,1); BAR_END(); } \
} while (0)

template <typename OutT>
__global__ __launch_bounds__(512, 2) void gemm_nt_256(
    const __bf16* __restrict__ A,    // [M x 512] row-major
    const __bf16* __restrict__ B,    // [N x 512] row-major  (C = A * B^T)
    OutT* __restrict__ C,            // [M x ldc] row-major
    const float* __restrict__ bias,  // nullptr, or [64]: adds bias[col & 63]
    int ldc, int mtiles,             // m-tiles per z-slice (m-minor tile order)
    long sA, long sB, long sC)       // per-z strides (elements)
{
    __shared__ __bf16 lds[2][2][BM * BK];   // [dbuf][A/B][256*64] = 128 KiB

    const int tid  = threadIdx.x;
    const int lane = tid & 63;
    const int wave = tid >> 6;        // 0..7
    const int wm   = wave & 1;        // 2 M-waves  (128 rows each)
    const int wn   = wave >> 1;       // 4 N-waves  (64 cols each)
    const int lcol = lane & 15;
    const int krow = (lane >> 4) & 3;

    // Bijective XCD swizzle over the flattened grid (m204 formula).
    long flat = (long)blockIdx.z * gridDim.x + blockIdx.x;
    long nwg  = (long)gridDim.x * gridDim.z;
    long q = nwg >> 3, r = nwg & 7;
    long xcd = flat & 7, lo = flat >> 3;
    long sz = (xcd < r ? xcd * (q + 1) : r * (q + 1) + (xcd - r) * q) + lo;
    const int z   = (int)(sz / (long)gridDim.x);
    const int rem = (int)(sz % (long)gridDim.x);
    const int n0 = (rem / mtiles) * BN;   // m-minor: same n-tile (W panel)
    const int m0 = (rem % mtiles) * BM;   // stays on one XCD's L2

    A += (long)z * sA + (long)m0 * KDIM;
    B += (long)z * sB + (long)n0 * KDIM;
    C += (long)z * sC;

    // Staging slice: thread covers rows {tid>>3, tid>>3 + 64} of a 128-row
    // half-tile, 16 B at col8 = tid&7.  XOR-swizzled LDS byte offset.
    const int srow  = tid >> 3;
    const int sbyte = srow * 128 + (((tid & 7) * 16) ^ ((srow & 7) << 4));
    const __bf16* gA = A + (long)srow * KDIM + (tid & 7) * 8;
    const __bf16* gB = B + (long)srow * KDIM + (tid & 7) * 8;

    bf16x8 rs[3][2];                  // 3-half-tile in-flight FIFO ring
    f32x4 acc[8][4] = {};

    // ---- prologue: write tile0 into buf0; leave t1.h0-h2 loads in flight ----
    STAGE_L(0, 0, 0); STAGE_L(1, 0, 1); STAGE_L(2, 0, 2);
    VMW(4); STAGE_W(0, 0, 0); STAGE_L(0, 0, 3);
    VMW(4); STAGE_W(1, 0, 1); STAGE_L(1, 1, 0);
    VMW(4); STAGE_W(2, 0, 2); STAGE_L(2, 1, 1);
    VMW(4); STAGE_W(0, 0, 3); STAGE_L(0, 1, 2);
    LGKM0();
    __builtin_amdgcn_s_barrier();
    __builtin_amdgcn_sched_barrier(0);

    // ---- main: tiles 0..5 with full staging (slots = (c+1)%3) ----
    ITER_UNIFORM(0, 1,2,0,1,2,0,1,2);
    ITER_UNIFORM(1, 0,1,2,0,1,2,0,1);
    ITER_UNIFORM(2, 2,0,1,2,0,1,2,0);

    // ---- iteration 3: tiles 6 (buf0) + 7 (buf1), draining ----
    { bf16x8 af[4][2], bfr[2][2];
      RD_A(0,0); RD_B(0,0);
      VMW(4); STAGE_W(1, 1, 0); STAGE_L(1, 7, 3);
      BAR_MID(); MFMA_Q(0,0); BAR_END();
      RD_B(0,1);
      VMW(4); STAGE_W(2, 1, 1);
      BAR_MID(); MFMA_Q(0,1); BAR_END();
      RD_A(0,1); RD_B(0,0);
      VMW(2); STAGE_W(0, 1, 2);
      BAR_MID(); MFMA_Q(1,0); BAR_END();
      RD_B(0,1);
      VMW(0); STAGE_W(1, 1, 3);
      BAR_MID(); MFMA_Q(1,1); BAR_END(); }
    { bf16x8 af[4][2], bfr[2][2];   // tile 7: reads only, no barriers needed
      RD_A(1,0); RD_B(1,0); MFMA_Q(0,0);
      RD_B(1,1);            MFMA_Q(0,1);
      RD_A(1,1); RD_B(1,0); MFMA_Q(1,0);
      RD_B(1,1);            MFMA_Q(1,1); }

    // Epilogue. C/D layout (16x16): col = lane&15, row = (lane>>4)*4 + reg.
    // j innermost: each 128B line of C is completed by 4 consecutive stores.
    float badd[4];
#pragma unroll
    for (int j = 0; j < 4; ++j)
        badd[j] = bias ? bias[j * 16 + lcol] : 0.f;
#pragma unroll
    for (int i = 0; i < 8; ++i) {
#pragma unroll
        for (int rr = 0; rr < 4; ++rr) {
            const int row = m0 + wm * 128 + i * 16 + krow * 4 + rr;
            OutT* cp = C + (long)row * ldc + n0 + wn * 64 + lcol;
#pragma unroll
            for (int j = 0; j < 4; ++j)
                cp[j * 16] = (OutT)(acc[i][j][rr] + badd[j]);
        }
    }
}

extern "C" void kernel_launch(void* const* d_in, const int* in_sizes, int n_in,
                              void* d_out, int out_size, void* d_ws, size_t ws_size,
                              hipStream_t stream)
{
    (void)in_sizes; (void)n_in; (void)out_size;
    const float* x1f = (const float*)d_in[0];  // [8,256,512]
    const float* x2f = (const float*)d_in[1];  // [8,256,512]
    const float* Wf  = (const float*)d_in[2];  // [64,512,512]
    const float* bs  = (const float*)d_in[3];  // [64]
    float* out = (float*)d_out;                // [8,256,256,64]

    const long N_W = 64L * 512 * 512;
    const long N_X = 8L * 256 * 512;
    __bf16* Wb  = (__bf16*)d_ws;
    __bf16* x1b = Wb + N_W;
    __bf16* x2b = x1b + N_X;
    __bf16* S   = x2b + N_X;
    const size_t head_bytes = (size_t)(N_W + 2 * N_X) * sizeof(__bf16); // 36 MiB

    f32_to_bf16_kernel<<<2048, 256, 0, stream>>>(Wf,  Wb,  N_W / 8);
    f32_to_bf16_kernel<<<512,  256, 0, stream>>>(x1f, x1b, N_X / 8);
    f32_to_bf16_kernel<<<512,  256, 0, stream>>>(x2f, x2b, N_X / 8);

    const long ROWS_TOTAL = 2048;              // S rows = (b,j)
    const long ROW_ELEMS  = 32768;             // (k,p) per S row

    long rows_chunk = (ws_size > head_bytes)
        ? (long)((ws_size - head_bytes) / (ROW_ELEMS * sizeof(__bf16))) : 0;
    rows_chunk &= ~255L;
    if (rows_chunk < 256) rows_chunk = 256;
    if (rows_chunk > ROWS_TOTAL) rows_chunk = ROWS_TOTAL;

    for (long r0 = 0; r0 < ROWS_TOTAL; r0 += rows_chunk) {
        long rows = ROWS_TOTAL - r0;
        if (rows > rows_chunk) rows = rows_chunk;
        long nbc = rows >> 8;                  // whole b's this chunk
        int  mt  = (int)(rows >> 8);           // 256-row m-tiles

        // Stage A: S = X2b @ Wb^T.  M = rows, N = 32768, K = 512.
        dim3 gA((unsigned)((32768 / BN) * mt), 1, 1);
        gemm_nt_256<__bf16><<<gA, 512, 0, stream>>>(
            x2b + r0 * KDIM, Wb, S, nullptr, 32768, mt, 0, 0, 0);

        // Stage B: z-batched over this chunk's b's -> fp32 out (+bias).
        dim3 gB2(16384 / BN, 1, (unsigned)nbc);
        gemm_nt_256<float><<<gB2, 512, 0, stream>>>(
            x1b + r0 * KDIM,                   // X1_b rows
            S,                                 // S_b as [16384 x 512]
            out + r0 * 16384,                  // out_b as [256 x 16384]
            bs, 16384, 1,
            256L * KDIM, 256L * ROW_ELEMS, 256L * 16384);
    }
}